// Round 4
// baseline (955.579 us; speedup 1.0000x reference)
//
#include <hip/hip_runtime.h>
#include <hip/hip_bf16.h>

#define N_NODES 100000
#define N_EDGES 3200000
#define N_GRAPHS 256

// ---------------- workspace layout (bytes, 512-aligned) ----------------
#define OFF_CNT       0u            // int[N]     in-degree counts (zeroed)
#define OFF_FILL      400384u       // int[N]     scatter fill counters (zeroed)
#define OFF_SUMS      800768u       // float[256*64] pool sums (zeroed)
#define OFF_CNTF      866304u       // float[256] pool counts (zeroed)
#define ZERO_BYTES    867328u
#define OFF_ROWPTR    867328u       // int[N+1]
#define OFF_DINV      1267712u      // float[N]
#define OFF_BLKSUM    1668096u      // int[128]
#define OFF_BLKOFF    1668608u      // int[128]
#define OFF_COL       1669120u      // int[E]
#define OFF_XS1       14469120u     // float[N*8]
#define OFF_Z1        17669120u     // float[N*8]
#define OFF_BUFQ      20869120u     // float[N*64]  xs2, later ys
#define OFF_BUFR      46469120u     // float[N*64]  z2, later z3
// total ~72 MB

__global__ void zero_kernel(int* p, int n) {
    int i = blockIdx.x * 256 + threadIdx.x;
    if (i < n) p[i] = 0;
}

__global__ void count_kernel(const int* __restrict__ dst, int* __restrict__ cnt, int E) {
    int e = blockIdx.x * 256 + threadIdx.x;
    if (e < E) atomicAdd(&cnt[__builtin_nontemporal_load(&dst[e])], 1);
}

// ---- 3-phase exclusive scan of cnt[N] -> row_ptr[N+1]; also dinv = rsqrt(cnt+1)
__global__ void scanA_kernel(const int* __restrict__ cnt, int* __restrict__ row_ptr,
                             int* __restrict__ blockSum, float* __restrict__ dinv, int n) {
    __shared__ int s[1024];
    int t = threadIdx.x;
    int i = blockIdx.x * 1024 + t;
    int v = (i < n) ? cnt[i] : 0;
    s[t] = v;
    __syncthreads();
    for (int off = 1; off < 1024; off <<= 1) {
        int add = (t >= off) ? s[t - off] : 0;
        __syncthreads();
        s[t] += add;
        __syncthreads();
    }
    if (i < n) {
        row_ptr[i] = s[t] - v;                 // block-local exclusive
        dinv[i] = rsqrtf((float)(v + 1));
    }
    if (t == 1023) blockSum[blockIdx.x] = s[t];
}

__global__ void scanB_kernel(const int* __restrict__ blockSum, int* __restrict__ blockOff,
                             int* __restrict__ row_ptr, int nb, int n) {
    __shared__ int s[128];
    int t = threadIdx.x;
    int v = (t < nb) ? blockSum[t] : 0;
    s[t] = v;
    __syncthreads();
    for (int off = 1; off < 128; off <<= 1) {
        int add = (t >= off) ? s[t - off] : 0;
        __syncthreads();
        s[t] += add;
        __syncthreads();
    }
    blockOff[t] = s[t] - v;                    // exclusive
    if (t == 127) row_ptr[n] = s[127];         // total = E
}

__global__ void scanC_kernel(int* __restrict__ row_ptr, const int* __restrict__ blockOff, int n) {
    int i = blockIdx.x * 1024 + threadIdx.x;
    if (i < n) row_ptr[i] += blockOff[blockIdx.x];
}

// XCD-sliced scatter + NON-TEMPORAL edge reads. Slicing keeps each slice's
// col window (~1.6 MB) inside one XCD's 4 MiB L2; nt loads keep the 12.8 MB
// dst/src streams from evicting those partially-filled col lines (R2 showed
// slicing alone left 172 MB of HBM writes -- the stream was the evictor).
#define SCAT_EPB (256 * 16)   // edges per block per slice
__global__ __launch_bounds__(256) void scatter_kernel(
        const int* __restrict__ src, const int* __restrict__ dst,
        const int* __restrict__ row_ptr, int* __restrict__ fill,
        int* __restrict__ col, int E) {
    int slice = blockIdx.x & 7;
    int chunk = blockIdx.x >> 3;
    int lo = slice * (N_NODES / 8);
    int hi = lo + (N_NODES / 8);          // N_NODES % 8 == 0
    int base = chunk * SCAT_EPB + threadIdx.x;
#pragma unroll
    for (int k = 0; k < 16; ++k) {
        int e = base + k * 256;
        if (e < E) {
            int d = __builtin_nontemporal_load(&dst[e]);
            if (d >= lo && d < hi) {
                int p = row_ptr[d] + atomicAdd(&fill[d], 1);
                col[p] = __builtin_nontemporal_load(&src[e]);
            }
        }
    }
}

__global__ void scale_x8_kernel(const float* __restrict__ x, const float* __restrict__ dinv,
                                float* __restrict__ xs, int n8) {
    int i = blockIdx.x * 256 + threadIdx.x;
    if (i < n8) xs[i] = x[i] * dinv[i >> 3];
}

// z_i[f] = dinv_i * ( xs_i[f] + sum_{e in CSR row i} xs[col[e]][f] )
// col is streamed (nt); xs gathers stay cacheable; z is streamed out (nt).
template <int D>
__global__ void agg_kernel(const float* __restrict__ xs, const int* __restrict__ row_ptr,
                           const int* __restrict__ col, const float* __restrict__ dinv,
                           float* __restrict__ z, int n) {
    constexpr int GROUPS = 256 / D;
    int node = blockIdx.x * GROUPS + threadIdx.x / D;
    int f = threadIdx.x % D;
    if (node >= n) return;
    int e0 = row_ptr[node], e1 = row_ptr[node + 1];
    float a0 = xs[node * D + f], a1 = 0.f, a2 = 0.f, a3 = 0.f;
    int e = e0;
    for (; e + 4 <= e1; e += 4) {
        int s0 = __builtin_nontemporal_load(&col[e]);
        int s1 = __builtin_nontemporal_load(&col[e + 1]);
        int s2 = __builtin_nontemporal_load(&col[e + 2]);
        int s3 = __builtin_nontemporal_load(&col[e + 3]);
        a0 += xs[s0 * D + f];
        a1 += xs[s1 * D + f];
        a2 += xs[s2 * D + f];
        a3 += xs[s3 * D + f];
    }
    for (; e < e1; ++e) a0 += xs[__builtin_nontemporal_load(&col[e]) * D + f];
    float v = dinv[node] * ((a0 + a1) + (a2 + a3));
    __builtin_nontemporal_store(v, &z[node * D + f]);
}

// Y[row, :] = opt_scale(dinv[row]) * opt_relu( X[row,:] @ W + opt_bias )
// (only used for layer 1: K=8, M=64)
template <int K, int M, bool BIAS, bool RELU, bool SCALE>
__global__ __launch_bounds__(256) void gemm_kernel(
        const float* __restrict__ X, const float* __restrict__ W,
        const float* __restrict__ b, const float* __restrict__ dinv,
        float* __restrict__ Y, int nrows) {
    constexpr int CG = M / 4;        // column groups of 4 (float4)
    constexpr int ROWS = 256 / CG;   // rows per tile
    __shared__ float Wl[K * M];
    __shared__ float Bl[M];
    __shared__ float Xl[ROWS * K];
    int tid = threadIdx.x;
    for (int i = tid; i < K * M; i += 256) Wl[i] = W[i];
    if (tid < M) {
        if constexpr (BIAS) Bl[tid] = b[tid];
        else Bl[tid] = 0.0f;
    }
    int ntiles = (nrows + ROWS - 1) / ROWS;
    for (int tile = blockIdx.x; tile < ntiles; tile += gridDim.x) {
        int row0 = tile * ROWS;
        __syncthreads();
        for (int i = tid; i < ROWS * K; i += 256) {
            int gi = row0 * K + i;
            Xl[i] = (gi < nrows * K) ? X[gi] : 0.0f;
        }
        __syncthreads();
        int r = tid / CG, cg = tid % CG;
        int row = row0 + r;
        if (row < nrows) {
            float4 acc;
            acc.x = Bl[cg * 4 + 0];
            acc.y = Bl[cg * 4 + 1];
            acc.z = Bl[cg * 4 + 2];
            acc.w = Bl[cg * 4 + 3];
#pragma unroll
            for (int k = 0; k < K; ++k) {
                float xv = Xl[r * K + k];
                const float4 w = *reinterpret_cast<const float4*>(&Wl[k * M + cg * 4]);
                acc.x += xv * w.x;
                acc.y += xv * w.y;
                acc.z += xv * w.z;
                acc.w += xv * w.w;
            }
            if constexpr (RELU) {
                acc.x = fmaxf(acc.x, 0.f); acc.y = fmaxf(acc.y, 0.f);
                acc.z = fmaxf(acc.z, 0.f); acc.w = fmaxf(acc.w, 0.f);
            }
            if constexpr (SCALE) {
                float d = dinv[row];
                acc.x *= d; acc.y *= d; acc.z *= d; acc.w *= d;
            }
            *reinterpret_cast<float4*>(&Y[row * M + cg * 4]) = acc;
        }
    }
}

// Fused layers 2+3 GEMM: Y = dinv * ( relu(X@W2 + b2) @ W3 )
// X: [N,64], W2: [64,128], W3: [128,64]. Per-row dependency only, so the
// 128-wide hidden stays in LDS per 16-row tile -- saves the 51.2 MB h2
// write + 51.2 MB read of the unfused version. LDS 78 KB -> 2 blocks/CU.
#define FT_ROWS 16
__global__ __launch_bounds__(256) void gemm23_kernel(
        const float* __restrict__ X, const float* __restrict__ W2,
        const float* __restrict__ b2, const float* __restrict__ W3,
        const float* __restrict__ dinv, float* __restrict__ Y, int nrows) {
    __shared__ float W2l[64 * 128];
    __shared__ float W3l[128 * 64];
    __shared__ float B2l[128];
    __shared__ float Xl[FT_ROWS * 64];
    __shared__ float Hl[FT_ROWS * 128];
    int tid = threadIdx.x;
    for (int i = tid; i < 64 * 128; i += 256) { W2l[i] = W2[i]; W3l[i] = W3[i]; }
    if (tid < 128) B2l[tid] = b2[tid];
    int r = tid >> 4, cg = tid & 15;   // 16 rows x 16 col-groups
    int ntiles = (nrows + FT_ROWS - 1) / FT_ROWS;
    for (int tile = blockIdx.x; tile < ntiles; tile += gridDim.x) {
        int row0 = tile * FT_ROWS;
        __syncthreads();   // covers weight preload (1st iter) + Hl reads (later iters)
        for (int i = tid; i < FT_ROWS * 64; i += 256) {
            int gi = row0 * 64 + i;
            Xl[i] = (gi < nrows * 64) ? X[gi] : 0.0f;
        }
        __syncthreads();
        {   // phase 1: H = relu(X@W2 + b2), 8 cols/thread
            float acc[8];
#pragma unroll
            for (int j = 0; j < 8; ++j) acc[j] = B2l[cg * 8 + j];
#pragma unroll
            for (int k = 0; k < 64; ++k) {
                float xv = Xl[r * 64 + k];
                const float4 wa = *reinterpret_cast<const float4*>(&W2l[k * 128 + cg * 8]);
                const float4 wb = *reinterpret_cast<const float4*>(&W2l[k * 128 + cg * 8 + 4]);
                acc[0] += xv * wa.x; acc[1] += xv * wa.y;
                acc[2] += xv * wa.z; acc[3] += xv * wa.w;
                acc[4] += xv * wb.x; acc[5] += xv * wb.y;
                acc[6] += xv * wb.z; acc[7] += xv * wb.w;
            }
#pragma unroll
            for (int j = 0; j < 8; ++j) Hl[r * 128 + cg * 8 + j] = fmaxf(acc[j], 0.0f);
        }
        __syncthreads();
        {   // phase 2: Y = H@W3 * dinv, 4 cols/thread
            float4 acc = make_float4(0.f, 0.f, 0.f, 0.f);
#pragma unroll
            for (int k = 0; k < 128; ++k) {
                float hv = Hl[r * 128 + k];
                const float4 w = *reinterpret_cast<const float4*>(&W3l[k * 64 + cg * 4]);
                acc.x += hv * w.x; acc.y += hv * w.y;
                acc.z += hv * w.z; acc.w += hv * w.w;
            }
            int row = row0 + r;
            if (row < nrows) {
                float d = dinv[row];
                acc.x *= d; acc.y *= d; acc.z *= d; acc.w *= d;
                *reinterpret_cast<float4*>(&Y[row * 64 + cg * 4]) = acc;
            }
        }
    }
}

// h3 = relu(z3 + b3); pool sums/counts per graph (batch sorted ->
// register-accumulate per graph-run, ~90K atomics total).
#define POOL_NPB 1024   // nodes per block
__global__ __launch_bounds__(256) void pool_kernel(
        const float* __restrict__ z3, const float* __restrict__ b3,
        const int* __restrict__ batch, float* __restrict__ sums,
        float* __restrict__ cntf, int n) {
    int wave = threadIdx.x >> 6;
    int lane = threadIdx.x & 63;   // feature index
    int node0 = blockIdx.x * POOL_NPB;
    int nodeEnd = node0 + POOL_NPB;
    if (nodeEnd > n) nodeEnd = n;
    float bias = b3[lane];
    float acc = 0.0f, cnt = 0.0f;
    int curg = -1;
    for (int node = node0 + wave; node < nodeEnd; node += 4) {
        int g = batch[node];               // wave-uniform (lane = feature)
        if (g != curg) {                   // wave-uniform branch
            if (curg >= 0) {
                atomicAdd(&sums[curg * 64 + lane], acc);
                if (lane == 0) atomicAdd(&cntf[curg], cnt);
            }
            curg = g; acc = 0.0f; cnt = 0.0f;
        }
        acc += fmaxf(__builtin_nontemporal_load(&z3[node * 64 + lane]) + bias, 0.0f);
        cnt += 1.0f;
    }
    if (curg >= 0) {
        atomicAdd(&sums[curg * 64 + lane], acc);
        if (lane == 0) atomicAdd(&cntf[curg], cnt);
    }
}

// per-graph: g = sums/max(cnt,1); hid = relu(g@Wl1+bl1); out = hid@Wl2+bl2
__global__ void mlp_kernel(const float* __restrict__ sums, const float* __restrict__ cntf,
                           const float* __restrict__ Wl1, const float* __restrict__ bl1,
                           const float* __restrict__ Wl2, const float* __restrict__ bl2,
                           float* __restrict__ out) {
    __shared__ float gv[64];
    __shared__ float hid[32];
    int g = blockIdx.x, t = threadIdx.x;
    float denom = fmaxf(cntf[g], 1.0f);
    gv[t] = sums[g * 64 + t] / denom;
    __syncthreads();
    if (t < 32) {
        float a = bl1[t];
#pragma unroll
        for (int k = 0; k < 64; ++k) a += gv[k] * Wl1[k * 32 + t];
        hid[t] = fmaxf(a, 0.0f);
    }
    __syncthreads();
    if (t == 0) {
        float o = bl2[0];
#pragma unroll
        for (int k = 0; k < 32; ++k) o += hid[k] * Wl2[k];
        out[g] = o;
    }
}

extern "C" void kernel_launch(void* const* d_in, const int* in_sizes, int n_in,
                              void* d_out, int out_size, void* d_ws, size_t ws_size,
                              hipStream_t stream) {
    const float* x   = (const float*)d_in[0];
    const int* ei    = (const int*)d_in[1];
    const int* batch = (const int*)d_in[2];
    const float* W1  = (const float*)d_in[3];
    const float* b1  = (const float*)d_in[4];
    const float* W2  = (const float*)d_in[5];
    const float* b2  = (const float*)d_in[6];
    const float* W3  = (const float*)d_in[7];
    const float* b3  = (const float*)d_in[8];
    const float* Wl1 = (const float*)d_in[9];
    const float* bl1 = (const float*)d_in[10];
    const float* Wl2 = (const float*)d_in[11];
    const float* bl2 = (const float*)d_in[12];
    float* out = (float*)d_out;

    const int N = N_NODES;
    const int E = in_sizes[1] / 2;   // 3.2M
    const int* src = ei;
    const int* dst = ei + E;

    char* ws = (char*)d_ws;
    int*   cnt     = (int*)(ws + OFF_CNT);
    int*   fill    = (int*)(ws + OFF_FILL);
    float* sums    = (float*)(ws + OFF_SUMS);
    float* cntf    = (float*)(ws + OFF_CNTF);
    int*   row_ptr = (int*)(ws + OFF_ROWPTR);
    float* dinv    = (float*)(ws + OFF_DINV);
    int*   blkSum  = (int*)(ws + OFF_BLKSUM);
    int*   blkOff  = (int*)(ws + OFF_BLKOFF);
    int*   col     = (int*)(ws + OFF_COL);
    float* xs1     = (float*)(ws + OFF_XS1);
    float* z1      = (float*)(ws + OFF_Z1);
    float* bufQ    = (float*)(ws + OFF_BUFQ);   // xs2, later ys
    float* bufR    = (float*)(ws + OFF_BUFR);   // z2, later z3

    // zero counters/accumulators
    {
        int nz = ZERO_BYTES / 4;
        zero_kernel<<<(nz + 255) / 256, 256, 0, stream>>>((int*)ws, nz);
    }

    // CSR build
    count_kernel<<<(E + 255) / 256, 256, 0, stream>>>(dst, cnt, E);
    int nb = (N + 1023) / 1024;   // 98
    scanA_kernel<<<nb, 1024, 0, stream>>>(cnt, row_ptr, blkSum, dinv, N);
    scanB_kernel<<<1, 128, 0, stream>>>(blkSum, blkOff, row_ptr, nb, N);
    scanC_kernel<<<nb, 1024, 0, stream>>>(row_ptr, blkOff, N);
    {
        int chunks = (E + SCAT_EPB - 1) / SCAT_EPB;
        scatter_kernel<<<chunks * 8, 256, 0, stream>>>(src, dst, row_ptr, fill, col, E);
    }

    // Layer 1: xs1 = dinv*x ; z1 = agg(xs1) ; xs2 = dinv*relu(z1@W1+b1)
    scale_x8_kernel<<<(N * 8 + 255) / 256, 256, 0, stream>>>(x, dinv, xs1, N * 8);
    agg_kernel<8><<<(N + 31) / 32, 256, 0, stream>>>(xs1, row_ptr, col, dinv, z1, N);
    gemm_kernel<8, 64, true, true, true><<<2560, 256, 0, stream>>>(z1, W1, b1, dinv, bufQ, N);

    // Layer 2+3: z2 = agg(xs2) ; ys = dinv*(relu(z2@W2+b2)@W3) ; z3 = agg(ys)
    agg_kernel<64><<<(N + 3) / 4, 256, 0, stream>>>(bufQ, row_ptr, col, dinv, bufR, N);
    gemm23_kernel<<<2048, 256, 0, stream>>>(bufR, W2, b2, W3, dinv, bufQ, N);
    agg_kernel<64><<<(N + 3) / 4, 256, 0, stream>>>(bufQ, row_ptr, col, dinv, bufR, N);

    // Pool + MLP head
    pool_kernel<<<(N + POOL_NPB - 1) / POOL_NPB, 256, 0, stream>>>(bufR, b3, batch, sums, cntf, N);
    mlp_kernel<<<N_GRAPHS, 64, 0, stream>>>(sums, cntf, Wl1, bl1, Wl2, bl2, out);
}

// Round 5
// 725.594 us; speedup vs baseline: 1.3170x; 1.3170x over previous
//
#include <hip/hip_runtime.h>
#include <hip/hip_bf16.h>

#define N_NODES 100000
#define N_EDGES 3200000
#define N_GRAPHS 256
#define NB_BUCKETS 196      // ceil(100000 / 512)
#define BSHIFT 9            // 512 nodes per bucket
#define NBLK 256            // blocks for hist/bin passes

// ---------------- workspace layout (bytes) ----------------
#define OFF_SUMS      0u            // float[256*64] pool sums (zeroed)
#define OFF_CNTF      65536u        // float[256] pool counts (zeroed)
#define ZERO_BYTES    66560u
#define OFF_HIST      66560u        // int[196*256] (bucket-major) per-(bucket,block) counts
#define OFF_ROWPTR    267264u       // int[N+1]
#define OFF_DINV      667648u       // float[N]
#define OFF_COL       1068032u      // int[E]
#define OFF_XS1       13868032u     // float[N*8]
#define OFF_Z1        17068032u     // float[N*8]
#define OFF_BUFQ      20268032u     // float[N*64]  xs2, later z3
#define OFF_BUFR      45868032u     // float[N*64]  z2, later ys
#define OFF_BUFP      71468032u     // float[N*128] h2; ALIASED: int2 pairs[E] (dead before h2 written)
#define OFF_PAIRS     OFF_BUFP
// total ~122.7 MB (<= 123.3 MB proven in R0-R3)

__global__ void zero_kernel(int* p, int n) {
    int i = blockIdx.x * 256 + threadIdx.x;
    if (i < n) p[i] = 0;
}

// ---- P1: per-(bucket,block) histogram of dst. No global atomics.
__global__ __launch_bounds__(256) void hist_kernel(const int* __restrict__ dst,
                                                   int* __restrict__ hist, int E, int epb) {
    __shared__ int h[NB_BUCKETS];
    int t = threadIdx.x, blk = blockIdx.x;
    if (t < NB_BUCKETS) h[t] = 0;
    __syncthreads();
    int e0 = blk * epb, e1 = min(e0 + epb, E);
    for (int e = e0 + t; e < e1; e += 256)
        atomicAdd(&h[__builtin_nontemporal_load(&dst[e]) >> BSHIFT], 1);
    __syncthreads();
    if (t < NB_BUCKETS) hist[t * NBLK + blk] = h[t];
}

// ---- P2: in-place exclusive scan of hist[196*256] (bucket-major).
// After this, hist[b*256+blk] = global offset of (bucket b, block blk)'s
// pair range; hist[b*256] is also bucket b's CSR segment base.
__global__ __launch_bounds__(1024) void scanhist_kernel(int* __restrict__ hist) {
    const int TOT = NB_BUCKETS * NBLK;     // 50176 = 1024*49
    const int CH = TOT / 1024;             // 49
    __shared__ int s[1024];
    int t = threadIdx.x;
    int base = t * CH;
    int sum = 0;
    for (int j = 0; j < CH; ++j) sum += hist[base + j];
    int v = sum;
    s[t] = v;
    __syncthreads();
    for (int off = 1; off < 1024; off <<= 1) {
        int add = (t >= off) ? s[t - off] : 0;
        __syncthreads();
        s[t] += add;
        __syncthreads();
    }
    int run = s[t] - v;                    // exclusive prefix of this chunk
    for (int j = 0; j < CH; ++j) {
        int tmp = hist[base + j];
        hist[base + j] = run;
        run += tmp;
    }
}

// ---- P3: bin edges into bucket-grouped (src,dst) pairs. Each block writes
// only into its private per-bucket subranges (block output ~100 KB,
// L2-resident -> full-line writebacks, no write amplification).
__global__ __launch_bounds__(256) void bin_kernel(const int* __restrict__ src,
                                                  const int* __restrict__ dst,
                                                  const int* __restrict__ hist,
                                                  int2* __restrict__ pairs, int E, int epb) {
    __shared__ int cur[NB_BUCKETS];
    int t = threadIdx.x, blk = blockIdx.x;
    if (t < NB_BUCKETS) cur[t] = hist[t * NBLK + blk];
    __syncthreads();
    int e0 = blk * epb, e1 = min(e0 + epb, E);
    for (int e = e0 + t; e < e1; e += 256) {
        int d = __builtin_nontemporal_load(&dst[e]);
        int sv = __builtin_nontemporal_load(&src[e]);
        int pos = atomicAdd(&cur[d >> BSHIFT], 1);
        pairs[pos] = make_int2(sv, d);
    }
}

// ---- P4: per-bucket CSR finalize. One block per bucket (512 threads).
// Computes local degree hist, local scan -> row_ptr & dinv, then scatters
// col within the bucket's ~65 KB window using LDS fill counters.
// Replaces count_kernel + global scans + global-atomic scatter entirely.
__global__ __launch_bounds__(512) void csr_kernel(const int2* __restrict__ pairs,
                                                  const int* __restrict__ hist,
                                                  int* __restrict__ row_ptr,
                                                  float* __restrict__ dinv,
                                                  int* __restrict__ col, int E) {
    __shared__ int cntL[512];
    __shared__ int rsL[512];
    __shared__ int fillL[512];
    int t = threadIdx.x, b = blockIdx.x;
    int lo = b << BSHIFT;
    int nloc = min(512, N_NODES - lo);
    int start = hist[b * NBLK];
    int end = (b == NB_BUCKETS - 1) ? E : hist[(b + 1) * NBLK];
    cntL[t] = 0;
    fillL[t] = 0;
    __syncthreads();
    for (int e = start + t; e < end; e += 512)
        atomicAdd(&cntL[pairs[e].y - lo], 1);
    __syncthreads();
    int v = cntL[t];
    __syncthreads();
    for (int off = 1; off < 512; off <<= 1) {     // inclusive scan (Hillis-Steele)
        int add = (t >= off) ? cntL[t - off] : 0;
        __syncthreads();
        cntL[t] += add;
        __syncthreads();
    }
    int rowstart = start + cntL[t] - v;           // exclusive + bucket base
    rsL[t] = rowstart;
    if (t < nloc) {
        row_ptr[lo + t] = rowstart;
        dinv[lo + t] = rsqrtf((float)(v + 1));
    }
    if (b == NB_BUCKETS - 1 && t == 0) row_ptr[N_NODES] = E;
    __syncthreads();
    for (int e = start + t; e < end; e += 512) {
        int2 p = pairs[e];
        int dl = p.y - lo;
        int pos = rsL[dl] + atomicAdd(&fillL[dl], 1);
        col[pos] = p.x;
    }
}

__global__ void scale_x8_kernel(const float* __restrict__ x, const float* __restrict__ dinv,
                                float* __restrict__ xs, int n8) {
    int i = blockIdx.x * 256 + threadIdx.x;
    if (i < n8) xs[i] = x[i] * dinv[i >> 3];
}

// z_i[f] = dinv_i * ( xs_i[f] + sum_{e in CSR row i} xs[col[e]][f] )
// col streamed (nt); xs gathers cacheable; z stored normally (consumed by
// the next kernel -- nt store here regressed R4).
template <int D>
__global__ void agg_kernel(const float* __restrict__ xs, const int* __restrict__ row_ptr,
                           const int* __restrict__ col, const float* __restrict__ dinv,
                           float* __restrict__ z, int n) {
    constexpr int GROUPS = 256 / D;
    int node = blockIdx.x * GROUPS + threadIdx.x / D;
    int f = threadIdx.x % D;
    if (node >= n) return;
    int e0 = row_ptr[node], e1 = row_ptr[node + 1];
    float a0 = xs[node * D + f], a1 = 0.f, a2 = 0.f, a3 = 0.f;
    int e = e0;
    for (; e + 4 <= e1; e += 4) {
        int s0 = __builtin_nontemporal_load(&col[e]);
        int s1 = __builtin_nontemporal_load(&col[e + 1]);
        int s2 = __builtin_nontemporal_load(&col[e + 2]);
        int s3 = __builtin_nontemporal_load(&col[e + 3]);
        a0 += xs[s0 * D + f];
        a1 += xs[s1 * D + f];
        a2 += xs[s2 * D + f];
        a3 += xs[s3 * D + f];
    }
    for (; e < e1; ++e) a0 += xs[__builtin_nontemporal_load(&col[e]) * D + f];
    z[node * D + f] = dinv[node] * ((a0 + a1) + (a2 + a3));
}

// Y[row, :] = opt_scale(dinv[row]) * opt_relu( X[row,:] @ W + opt_bias )
template <int K, int M, bool BIAS, bool RELU, bool SCALE>
__global__ __launch_bounds__(256) void gemm_kernel(
        const float* __restrict__ X, const float* __restrict__ W,
        const float* __restrict__ b, const float* __restrict__ dinv,
        float* __restrict__ Y, int nrows) {
    constexpr int CG = M / 4;        // column groups of 4 (float4)
    constexpr int ROWS = 256 / CG;   // rows per tile
    __shared__ float Wl[K * M];
    __shared__ float Bl[M];
    __shared__ float Xl[ROWS * K];
    int tid = threadIdx.x;
    for (int i = tid; i < K * M; i += 256) Wl[i] = W[i];
    if (tid < M) {
        if constexpr (BIAS) Bl[tid] = b[tid];
        else Bl[tid] = 0.0f;
    }
    int ntiles = (nrows + ROWS - 1) / ROWS;
    for (int tile = blockIdx.x; tile < ntiles; tile += gridDim.x) {
        int row0 = tile * ROWS;
        __syncthreads();
        for (int i = tid; i < ROWS * K; i += 256) {
            int gi = row0 * K + i;
            Xl[i] = (gi < nrows * K) ? X[gi] : 0.0f;
        }
        __syncthreads();
        int r = tid / CG, cg = tid % CG;
        int row = row0 + r;
        if (row < nrows) {
            float4 acc;
            acc.x = Bl[cg * 4 + 0];
            acc.y = Bl[cg * 4 + 1];
            acc.z = Bl[cg * 4 + 2];
            acc.w = Bl[cg * 4 + 3];
#pragma unroll
            for (int k = 0; k < K; ++k) {
                float xv = Xl[r * K + k];
                const float4 w = *reinterpret_cast<const float4*>(&Wl[k * M + cg * 4]);
                acc.x += xv * w.x;
                acc.y += xv * w.y;
                acc.z += xv * w.z;
                acc.w += xv * w.w;
            }
            if constexpr (RELU) {
                acc.x = fmaxf(acc.x, 0.f); acc.y = fmaxf(acc.y, 0.f);
                acc.z = fmaxf(acc.z, 0.f); acc.w = fmaxf(acc.w, 0.f);
            }
            if constexpr (SCALE) {
                float d = dinv[row];
                acc.x *= d; acc.y *= d; acc.z *= d; acc.w *= d;
            }
            *reinterpret_cast<float4*>(&Y[row * M + cg * 4]) = acc;
        }
    }
}

// h3 = relu(z3 + b3); pool sums/counts per graph (batch sorted ->
// register-accumulate per graph-run, ~90K atomics total).
#define POOL_NPB 1024   // nodes per block
__global__ __launch_bounds__(256) void pool_kernel(
        const float* __restrict__ z3, const float* __restrict__ b3,
        const int* __restrict__ batch, float* __restrict__ sums,
        float* __restrict__ cntf, int n) {
    int wave = threadIdx.x >> 6;
    int lane = threadIdx.x & 63;   // feature index
    int node0 = blockIdx.x * POOL_NPB;
    int nodeEnd = node0 + POOL_NPB;
    if (nodeEnd > n) nodeEnd = n;
    float bias = b3[lane];
    float acc = 0.0f, cnt = 0.0f;
    int curg = -1;
    for (int node = node0 + wave; node < nodeEnd; node += 4) {
        int g = batch[node];               // wave-uniform (lane = feature)
        if (g != curg) {                   // wave-uniform branch
            if (curg >= 0) {
                atomicAdd(&sums[curg * 64 + lane], acc);
                if (lane == 0) atomicAdd(&cntf[curg], cnt);
            }
            curg = g; acc = 0.0f; cnt = 0.0f;
        }
        acc += fmaxf(__builtin_nontemporal_load(&z3[node * 64 + lane]) + bias, 0.0f);
        cnt += 1.0f;
    }
    if (curg >= 0) {
        atomicAdd(&sums[curg * 64 + lane], acc);
        if (lane == 0) atomicAdd(&cntf[curg], cnt);
    }
}

// per-graph: g = sums/max(cnt,1); hid = relu(g@Wl1+bl1); out = hid@Wl2+bl2
__global__ void mlp_kernel(const float* __restrict__ sums, const float* __restrict__ cntf,
                           const float* __restrict__ Wl1, const float* __restrict__ bl1,
                           const float* __restrict__ Wl2, const float* __restrict__ bl2,
                           float* __restrict__ out) {
    __shared__ float gv[64];
    __shared__ float hid[32];
    int g = blockIdx.x, t = threadIdx.x;
    float denom = fmaxf(cntf[g], 1.0f);
    gv[t] = sums[g * 64 + t] / denom;
    __syncthreads();
    if (t < 32) {
        float a = bl1[t];
#pragma unroll
        for (int k = 0; k < 64; ++k) a += gv[k] * Wl1[k * 32 + t];
        hid[t] = fmaxf(a, 0.0f);
    }
    __syncthreads();
    if (t == 0) {
        float o = bl2[0];
#pragma unroll
        for (int k = 0; k < 32; ++k) o += hid[k] * Wl2[k];
        out[g] = o;
    }
}

extern "C" void kernel_launch(void* const* d_in, const int* in_sizes, int n_in,
                              void* d_out, int out_size, void* d_ws, size_t ws_size,
                              hipStream_t stream) {
    const float* x   = (const float*)d_in[0];
    const int* ei    = (const int*)d_in[1];
    const int* batch = (const int*)d_in[2];
    const float* W1  = (const float*)d_in[3];
    const float* b1  = (const float*)d_in[4];
    const float* W2  = (const float*)d_in[5];
    const float* b2  = (const float*)d_in[6];
    const float* W3  = (const float*)d_in[7];
    const float* b3  = (const float*)d_in[8];
    const float* Wl1 = (const float*)d_in[9];
    const float* bl1 = (const float*)d_in[10];
    const float* Wl2 = (const float*)d_in[11];
    const float* bl2 = (const float*)d_in[12];
    float* out = (float*)d_out;

    const int N = N_NODES;
    const int E = in_sizes[1] / 2;   // 3.2M
    const int* src = ei;
    const int* dst = ei + E;

    char* ws = (char*)d_ws;
    float* sums    = (float*)(ws + OFF_SUMS);
    float* cntf    = (float*)(ws + OFF_CNTF);
    int*   hist    = (int*)(ws + OFF_HIST);
    int*   row_ptr = (int*)(ws + OFF_ROWPTR);
    float* dinv    = (float*)(ws + OFF_DINV);
    int*   col     = (int*)(ws + OFF_COL);
    float* xs1     = (float*)(ws + OFF_XS1);
    float* z1      = (float*)(ws + OFF_Z1);
    float* bufQ    = (float*)(ws + OFF_BUFQ);   // xs2, later z3
    float* bufR    = (float*)(ws + OFF_BUFR);   // z2, later ys
    float* bufP    = (float*)(ws + OFF_BUFP);   // h2
    int2*  pairs   = (int2*)(ws + OFF_PAIRS);   // aliases bufP (dead before h2)

    // zero pool accumulators only (CSR build needs no pre-zeroed globals)
    zero_kernel<<<(ZERO_BYTES / 4 + 255) / 256, 256, 0, stream>>>((int*)ws, ZERO_BYTES / 4);

    // CSR build: hist -> scan -> bin -> per-bucket finalize
    int epb = (E + NBLK - 1) / NBLK;   // 12500
    hist_kernel<<<NBLK, 256, 0, stream>>>(dst, hist, E, epb);
    scanhist_kernel<<<1, 1024, 0, stream>>>(hist);
    bin_kernel<<<NBLK, 256, 0, stream>>>(src, dst, hist, pairs, E, epb);
    csr_kernel<<<NB_BUCKETS, 512, 0, stream>>>(pairs, hist, row_ptr, dinv, col, E);

    // Layer 1: xs1 = dinv*x ; z1 = agg(xs1) ; xs2 = dinv*relu(z1@W1+b1)
    scale_x8_kernel<<<(N * 8 + 255) / 256, 256, 0, stream>>>(x, dinv, xs1, N * 8);
    agg_kernel<8><<<(N + 31) / 32, 256, 0, stream>>>(xs1, row_ptr, col, dinv, z1, N);
    gemm_kernel<8, 64, true, true, true><<<2560, 256, 0, stream>>>(z1, W1, b1, dinv, bufQ, N);

    // Layer 2: z2 = agg(xs2) ; h2 = relu(z2@W2+b2)
    agg_kernel<64><<<(N + 3) / 4, 256, 0, stream>>>(bufQ, row_ptr, col, dinv, bufR, N);
    gemm_kernel<64, 128, true, true, false><<<2560, 256, 0, stream>>>(bufR, W2, b2, nullptr, bufP, N);

    // Layer 3: ys = dinv*(h2@W3) ; z3 = agg(ys)
    gemm_kernel<128, 64, false, false, true><<<2560, 256, 0, stream>>>(bufP, W3, nullptr, dinv, bufR, N);
    agg_kernel<64><<<(N + 3) / 4, 256, 0, stream>>>(bufR, row_ptr, col, dinv, bufQ, N);

    // Pool + MLP head
    pool_kernel<<<(N + POOL_NPB - 1) / POOL_NPB, 256, 0, stream>>>(bufQ, b3, batch, sums, cntf, N);
    mlp_kernel<<<N_GRAPHS, 64, 0, stream>>>(sums, cntf, Wl1, bl1, Wl2, bl2, out);
}